// Round 4
// baseline (294.169 us; speedup 1.0000x reference)
//
#include <hip/hip_runtime.h>
#include <stdint.h>
#include <type_traits>

typedef unsigned short u16;
using short8  = __attribute__((ext_vector_type(8))) short;
using floatx4 = __attribute__((ext_vector_type(4))) float;

__device__ __forceinline__ u16 f2bf(float f) {
    unsigned u = __float_as_uint(f);
    u += 0x7fff + ((u >> 16) & 1);   // round-to-nearest-even
    return (u16)(u >> 16);
}
__device__ __forceinline__ float bf2f(u16 h) {
    return __uint_as_float(((unsigned)h) << 16);
}

// async global->LDS, 16B per lane (global_load_lds_dwordx4)
__device__ __forceinline__ void gload_lds16(const void* g, void* l) {
    auto gp = reinterpret_cast<const __attribute__((address_space(1))) unsigned int*>(
        reinterpret_cast<uintptr_t>(g));
    auto lp = reinterpret_cast<__attribute__((address_space(3))) unsigned int*>(
        reinterpret_cast<uintptr_t>(l));
    __builtin_amdgcn_global_load_lds(gp, lp, 16, 0, 0);
}

// 1) convert x f32 -> bf16 ----------------------------------------------------
__global__ __launch_bounds__(256) void cvt_f32_bf16_kernel(
        const float* __restrict__ in, u16* __restrict__ out) {
    long i = ((long)blockIdx.x * 256 + threadIdx.x) * 4;
    float4 v = *(const float4*)(in + i);
    ushort4 o;
    o.x = f2bf(v.x); o.y = f2bf(v.y); o.z = f2bf(v.z); o.w = f2bf(v.w);
    *(ushort4*)(out + i) = o;
}

// 2) W [1024][1024] f32 -> Wt bf16 [e][d] (transpose+convert), 3 weights ------
__global__ __launch_bounds__(256) void wt_kernel(
        const float* __restrict__ W0, const float* __restrict__ W1, const float* __restrict__ W2,
        u16* __restrict__ O0, u16* __restrict__ O1, u16* __restrict__ O2) {
    const float* W = blockIdx.z == 0 ? W0 : blockIdx.z == 1 ? W1 : W2;
    u16* O = blockIdx.z == 0 ? O0 : blockIdx.z == 1 ? O1 : O2;
    __shared__ float t[32][33];
    const int cx = threadIdx.x & 31, ry = threadIdx.x >> 5;
    const int d0 = blockIdx.x * 32, e0 = blockIdx.y * 32;
#pragma unroll
    for (int i = 0; i < 4; i++) t[ry + i * 8][cx] = W[(long)(d0 + ry + i * 8) * 1024 + e0 + cx];
    __syncthreads();
#pragma unroll
    for (int i = 0; i < 4; i++) O[(long)(e0 + ry + i * 8) * 1024 + d0 + cx] = f2bf(t[cx][ry + i * 8]);
}

// 3) 256x256 8-phase GEMM (m201 port): C = A[M][K] @ Bt[N][K]^T ---------------
// 8 waves (2M x 4N), wave tile 128x64, BK=64, 2 LDS dbufs (128 KiB total),
// XOR-swizzled LDS (linear gload_lds dest + inverse-swizzled global source),
// counted vmcnt(6) at phases 4/8 only, setprio(1) around MFMA clusters.
// Frags double-buffered in registers (each A/B half read from LDS once/K-tile,
// prefetched one phase ahead; compiler emits counted lgkmcnt).
// MODE 0: QKV fused (bias; Q,K row-major bf16; V written TRANSPOSED into Vt)
// MODE 1: scores (*scale, bf16 out, batched)
// MODE 2: PV (f32 out, batched)
template <int MODE>
__global__ __launch_bounds__(512, 2) void gemm8_kernel(
        const u16* __restrict__ A, const u16* __restrict__ Bt,
        void* __restrict__ out0, void* __restrict__ out1, void* __restrict__ out2,
        const float* __restrict__ b0, const float* __restrict__ b1, const float* __restrict__ b2,
        int K, int N, long sAb, long sBb, long sCb, float scale)
{
    extern __shared__ u16 lds[];   // [dbuf:2][ A(2 halves x 128 x 64) | B(2 halves x 128 x 64) ]
    const int tid = threadIdx.x, lane = tid & 63, wid = tid >> 6;
    const int wm = wid >> 2, wn = wid & 3;
    const int l15 = lane & 15, hib = (lane >> 4) * 16;   // byte col offset of frag

    // XCD-aware bijective swizzle (all grids have nwg % 8 == 0)
    const int nbx = gridDim.x;
    const int nwg = nbx * gridDim.y;
    int lin = blockIdx.y * nbx + blockIdx.x;
    lin = (lin & 7) * (nwg >> 3) + (lin >> 3);
    const long m0 = (long)(lin / nbx) * 256;
    const long n0 = (long)(lin % nbx) * 256;

    const u16* Ab = A + (long)blockIdx.z * sAb;
    const u16* Bb = Bt + (long)blockIdx.z * sBb;
    const long ldk = K;
    const int NT = K >> 6;          // K-tiles of 64

    // ---- staging: one "unit" = 16KB, 2 x gload_lds16 per thread ------------
    auto stA = [&](int dbuf, int S, int kt) {
#pragma unroll
        for (int i = 0; i < 2; ++i) {
            const int rl = tid >> 3;                    // 0..63
            const int R  = S * 64 + rl;                 // row within half
            const int cb = (tid & 7) * 16;
            const int scb = cb ^ ((R & 7) << 4);        // inverse swizzle on SOURCE
            const u16* src = Ab + (m0 + i * 128 + R) * ldk + (long)kt * 64 + (scb >> 1);
            u16* dst = lds + dbuf * 32768 + i * 8192 + S * 4096 + wid * 512;
            gload_lds16(src, dst);
        }
    };
    auto stB = [&](int dbuf, int NHs, int kt) {
#pragma unroll
        for (int i = 0; i < 2; ++i) {
            const int c = i * 2 + (wid >> 2);           // chunk 0..3 (wave-uniform)
            const int h = c >> 1, rb = (c & 1) * 64;
            const int w = (wid & 3) * 64 + lane;        // 0..255 within chunk
            const int r32 = w >> 3;                     // 0..31
            const int R = rb + NHs * 32 + r32;          // row within half
            const int cb = (w & 7) * 16;
            const int scb = cb ^ ((R & 7) << 4);
            const u16* src = Bb + (n0 + h * 128 + R) * ldk + (long)kt * 64 + (scb >> 1);
            u16* dst = lds + dbuf * 32768 + 16384 + h * 8192 + (rb + NHs * 32) * 64 + (wid & 3) * 512;
            gload_lds16(src, dst);
        }
    };

    floatx4 acc[8][4] = {};
    short8 afrA[4][2], afrB[4][2];   // A fragments, MH=0 / MH=1
    short8 bfrA[2][2], bfrB[2][2];   // B fragments, NH=0 / NH=1

    auto LA = [&](int dbuf, int MH, short8 (&dst)[4][2]) {
        const char* reg = (const char*)(lds + dbuf * 32768 + wm * 8192);
#pragma unroll
        for (int fm = 0; fm < 4; ++fm)
#pragma unroll
            for (int ks = 0; ks < 2; ++ks) {
                const int r = MH * 64 + fm * 16 + l15;
                const int cb = ks * 64 + hib;
                dst[fm][ks] = *(const short8*)(reg + r * 128 + (cb ^ ((r & 7) << 4)));
            }
    };
    auto LB = [&](int dbuf, int NH, short8 (&dst)[2][2]) {
        const char* reg = (const char*)(lds + dbuf * 32768 + 16384 + (wn >> 1) * 8192);
#pragma unroll
        for (int fn = 0; fn < 2; ++fn)
#pragma unroll
            for (int ks = 0; ks < 2; ++ks) {
                const int r = (wn & 1) * 64 + NH * 32 + fn * 16 + l15;
                const int cb = ks * 64 + hib;
                dst[fn][ks] = *(const short8*)(reg + r * 128 + (cb ^ ((r & 7) << 4)));
            }
    };
    auto MM = [&](short8 (&a)[4][2], short8 (&b)[2][2], int MH, int NH) {
        __builtin_amdgcn_s_setprio(1);
#pragma unroll
        for (int fm = 0; fm < 4; ++fm)
#pragma unroll
            for (int fn = 0; fn < 2; ++fn)
#pragma unroll
                for (int ks = 0; ks < 2; ++ks)
                    acc[MH * 4 + fm][NH * 2 + fn] = __builtin_amdgcn_mfma_f32_16x16x32_bf16(
                        a[fm][ks], b[fn][ks], acc[MH * 4 + fm][NH * 2 + fn], 0, 0, 0);
        __builtin_amdgcn_s_setprio(0);
    };

#define BAR() __builtin_amdgcn_s_barrier()

    // ---- prologue: stage kt0 fully + kt1 {A0, B1, A1}; keep 6 in flight -----
    stA(0, 0, 0); stA(0, 1, 0); stB(0, 0, 0); stB(0, 1, 0);
    stA(1, 0, 1); stB(1, 1, 1); stA(1, 1, 1);
    asm volatile("s_waitcnt vmcnt(6)");
    BAR();

    // ---- main loop: one iteration = 2 K-tiles = 8 phases --------------------
    // Stage slots & sync gates identical to the verified round-3 schedule;
    // ds_reads are hoisted to the earliest phase of their K-tile.
    auto pair = [&](auto LASTC, int kt0) {
        constexpr bool L = decltype(LASTC)::value;
        // ph1 (kt0, dbuf0): read A0,B0,B1
        LA(0, 0, afrA); LB(0, 0, bfrA); LB(0, 1, bfrB);
        stB(1, 0, kt0 + 1);
        BAR(); MM(afrA, bfrA, 0, 0); BAR();
        // ph2: read A1 (prefetch for ph3/4)
        LA(0, 1, afrB);
        if (!L) stA(0, 0, kt0 + 2);
        BAR(); MM(afrA, bfrB, 0, 1); BAR();
        // ph3: no reads
        if (!L) stB(0, 1, kt0 + 2);
        BAR(); MM(afrB, bfrB, 1, 1); BAR();
        // ph4: no reads; vmcnt gate for dbuf1
        if (!L) stA(0, 1, kt0 + 2);
        BAR(); MM(afrB, bfrA, 1, 0);
        if (L) asm volatile("s_waitcnt vmcnt(0)");
        else   asm volatile("s_waitcnt vmcnt(6)");
        BAR();
        // ph5 (kt0+1, dbuf1): read A0,B0,B1
        LA(1, 0, afrA); LB(1, 0, bfrA); LB(1, 1, bfrB);
        if (!L) stB(0, 0, kt0 + 2);
        BAR(); MM(afrA, bfrA, 0, 0); BAR();
        // ph6: read A1
        LA(1, 1, afrB);
        if (!L) stA(1, 0, kt0 + 3);
        BAR(); MM(afrA, bfrB, 0, 1); BAR();
        // ph7: no reads
        if (!L) stB(1, 1, kt0 + 3);
        BAR(); MM(afrB, bfrB, 1, 1); BAR();
        // ph8: no reads; vmcnt gate for dbuf0
        if (!L) stA(1, 1, kt0 + 3);
        BAR(); MM(afrB, bfrA, 1, 0);
        if (L) asm volatile("s_waitcnt vmcnt(0)");
        else   asm volatile("s_waitcnt vmcnt(6)");
        BAR();
    };

    const int NITER = NT >> 1;
    int it = 0;
    for (; it < NITER - 1; ++it) pair(std::false_type{}, 2 * it);
    pair(std::true_type{}, 2 * it);

#undef BAR

    // ---- epilogue: C/D layout col=lane&15, row=(lane>>4)*4+j (HW-verified) --
    const int cr = (lane >> 4) * 4, cc = l15;
    if (MODE == 0) {
        const int sel = (int)(n0 >> 10);   // 256 | 1024: block entirely in one of q/k/v
        const long nc0 = n0 & 1023;
        if (sel < 2) {
            // Q or K: row-major [8192][1024] bf16
            u16* O = (u16*)(sel == 0 ? out0 : out1);
            const float* bias = sel == 0 ? b0 : b1;
#pragma unroll
            for (int an = 0; an < 4; ++an) {
                const long col = nc0 + wn * 64 + an * 16 + cc;
                const float bvv = bias[col];
#pragma unroll
                for (int am = 0; am < 8; ++am) {
                    const long row = m0 + wm * 128 + am * 16 + cr;
#pragma unroll
                    for (int j = 0; j < 4; ++j)
                        O[(row + j) * 1024 + col] = f2bf(acc[am][an][j] + bvv);
                }
            }
        } else {
            // V: write TRANSPOSED into Vt[4][1024][2048]; j runs contiguous in t
            u16* O = (u16*)out2;
            const long b = m0 >> 11;           // batch (tile never crosses: 2048%256==0)
            const long tb = (m0 & 2047) + wm * 128;
#pragma unroll
            for (int an = 0; an < 4; ++an) {
                const long e = nc0 + wn * 64 + an * 16 + cc;
                const float bvv = b2[e];
                u16* Oe = O + b * 1024 * 2048 + e * 2048;
#pragma unroll
                for (int am = 0; am < 8; ++am) {
                    const long t = tb + am * 16 + cr;
                    ushort4 w;
                    w.x = f2bf(acc[am][an][0] + bvv);
                    w.y = f2bf(acc[am][an][1] + bvv);
                    w.z = f2bf(acc[am][an][2] + bvv);
                    w.w = f2bf(acc[am][an][3] + bvv);
                    *(ushort4*)(Oe + t) = w;   // t % 4 == 0 -> 8B aligned
                }
            }
        }
    } else {
#pragma unroll
        for (int an = 0; an < 4; ++an) {
            const long col = n0 + wn * 64 + an * 16 + cc;
#pragma unroll
            for (int am = 0; am < 8; ++am) {
                const long row = m0 + wm * 128 + am * 16 + cr;
#pragma unroll
                for (int j = 0; j < 4; ++j) {
                    const long idx = (long)blockIdx.z * sCb + (row + j) * (long)N + col;
                    if (MODE == 1) ((u16*)out0)[idx] = f2bf(acc[am][an][j] * scale);
                    else           ((float*)out0)[idx] = acc[am][an][j];
                }
            }
        }
    }
}

// 4) in-place row softmax over 2048 bf16 --------------------------------------
__global__ __launch_bounds__(256) void softmax_kernel(u16* __restrict__ S) {
    u16* p = S + (long)blockIdx.x * 2048;
    const int tid = threadIdx.x;
    union { int4 q; u16 u[8]; } in;
    in.q = *(const int4*)(p + tid * 8);
    float v[8];
#pragma unroll
    for (int i = 0; i < 8; i++) v[i] = bf2f(in.u[i]);
    float mx = v[0];
#pragma unroll
    for (int i = 1; i < 8; i++) mx = fmaxf(mx, v[i]);
#pragma unroll
    for (int off = 32; off; off >>= 1) mx = fmaxf(mx, __shfl_xor(mx, off));
    __shared__ float red[8];
    if ((tid & 63) == 0) red[tid >> 6] = mx;
    __syncthreads();
    mx = fmaxf(fmaxf(red[0], red[1]), fmaxf(red[2], red[3]));
    float s = 0.f;
#pragma unroll
    for (int i = 0; i < 8; i++) { v[i] = __expf(v[i] - mx); s += v[i]; }
#pragma unroll
    for (int off = 32; off; off >>= 1) s += __shfl_xor(s, off);
    if ((tid & 63) == 0) red[4 + (tid >> 6)] = s;
    __syncthreads();
    s = red[4] + red[5] + red[6] + red[7];
    const float inv = 1.f / s;
    union { int4 q; u16 u[8]; } out;
#pragma unroll
    for (int i = 0; i < 8; i++) out.u[i] = f2bf(v[i] * inv);
    *(int4*)(p + tid * 8) = out.q;
}

// -----------------------------------------------------------------------------
extern "C" void kernel_launch(void* const* d_in, const int* in_sizes, int n_in,
                              void* d_out, int out_size, void* d_ws, size_t ws_size,
                              hipStream_t stream) {
    const float* x  = (const float*)d_in[0];
    const float* Wq = (const float*)d_in[1];
    const float* bq = (const float*)d_in[2];
    const float* Wk = (const float*)d_in[3];
    const float* bk = (const float*)d_in[4];
    const float* Wv = (const float*)d_in[5];
    const float* bv = (const float*)d_in[6];
    float* out = (float*)d_out;

    char* ws = (char*)d_ws;
    const long MB = 1L << 20;
    u16* xb = (u16*)(ws);            // 16 MB  x bf16 [8192][1024]
    u16* wt = (u16*)(ws + 16 * MB);  // 6 MB   W{q,k,v}^T bf16 [3072][1024] stacked
    u16* Q  = (u16*)(ws + 22 * MB);  // 16 MB  [4][2048][1024]
    u16* Kb = (u16*)(ws + 38 * MB);  // 16 MB  [4][2048][1024]
    u16* Vt = (u16*)(ws + 54 * MB);  // 16 MB  [4][1024][2048]  (written directly by QKV)
    u16* Sc = (u16*)(ws + 70 * MB);  // 32 MB  scores/attn [4][2048][2048]

    // allow 128 KiB dynamic LDS (idempotent; host-side, capture-safe)
    (void)hipFuncSetAttribute((const void*)gemm8_kernel<0>, hipFuncAttributeMaxDynamicSharedMemorySize, 131072);
    (void)hipFuncSetAttribute((const void*)gemm8_kernel<1>, hipFuncAttributeMaxDynamicSharedMemorySize, 131072);
    (void)hipFuncSetAttribute((const void*)gemm8_kernel<2>, hipFuncAttributeMaxDynamicSharedMemorySize, 131072);

    // x -> bf16
    cvt_f32_bf16_kernel<<<8192, 256, 0, stream>>>(x, xb);
    // W -> Wt bf16 (transposed, stacked)
    wt_kernel<<<dim3(32, 32, 3), 256, 0, stream>>>(Wq, Wk, Wv, wt, wt + 1024 * 1024, wt + 2 * 1024 * 1024);
    // fused QKV: [8192][1024] @ [3072][1024]^T + bias (M=8192, N=3072, K=1024)
    // Q,K row-major; V written transposed into Vt
    gemm8_kernel<0><<<dim3(12, 32, 1), 512, 131072, stream>>>(
        xb, wt, Q, Kb, Vt, bq, bk, bv, 1024, 3072, 0, 0, 0, 1.f);
    // scores = (Q @ K^T) / 32, bf16, batched (M=N=2048, K=1024)
    gemm8_kernel<1><<<dim3(8, 8, 4), 512, 131072, stream>>>(
        Q, Kb, Sc, nullptr, nullptr, nullptr, nullptr, nullptr,
        1024, 2048, 2048L * 1024, 2048L * 1024, 2048L * 2048, 0.03125f);
    // softmax rows, in place
    softmax_kernel<<<8192, 256, 0, stream>>>(Sc);
    // out = attn @ V, f32 out, batched (M=2048, N=1024, K=2048)
    gemm8_kernel<2><<<dim3(4, 8, 4), 512, 131072, stream>>>(
        Sc, Vt, out, nullptr, nullptr, nullptr, nullptr, nullptr,
        2048, 1024, 2048L * 2048, 1024L * 2048, 2048L * 1024, 1.f);
}

// Round 5
// 184.071 us; speedup vs baseline: 1.5981x; 1.5981x over previous
//
#include <hip/hip_runtime.h>
#include <stdint.h>
#include <type_traits>

typedef unsigned short u16;
using short8  = __attribute__((ext_vector_type(8))) short;
using floatx4 = __attribute__((ext_vector_type(4))) float;

#define IC(n) (std::integral_constant<int, (n)>())

__device__ __forceinline__ u16 f2bf(float f) {
    unsigned u = __float_as_uint(f);
    u += 0x7fff + ((u >> 16) & 1);   // round-to-nearest-even
    return (u16)(u >> 16);
}
__device__ __forceinline__ float bf2f(u16 h) {
    return __uint_as_float(((unsigned)h) << 16);
}

// async global->LDS, 16B per lane (global_load_lds_dwordx4)
__device__ __forceinline__ void gload_lds16(const void* g, void* l) {
    auto gp = reinterpret_cast<const __attribute__((address_space(1))) unsigned int*>(
        reinterpret_cast<uintptr_t>(g));
    auto lp = reinterpret_cast<__attribute__((address_space(3))) unsigned int*>(
        reinterpret_cast<uintptr_t>(l));
    __builtin_amdgcn_global_load_lds(gp, lp, 16, 0, 0);
}

// 1) convert x f32 -> bf16 ----------------------------------------------------
__global__ __launch_bounds__(256) void cvt_f32_bf16_kernel(
        const float* __restrict__ in, u16* __restrict__ out) {
    long i = ((long)blockIdx.x * 256 + threadIdx.x) * 4;
    float4 v = *(const float4*)(in + i);
    ushort4 o;
    o.x = f2bf(v.x); o.y = f2bf(v.y); o.z = f2bf(v.z); o.w = f2bf(v.w);
    *(ushort4*)(out + i) = o;
}

// 2) W [1024][1024] f32 -> Wt bf16 [e][d] (transpose+convert), 3 weights ------
__global__ __launch_bounds__(256) void wt_kernel(
        const float* __restrict__ W0, const float* __restrict__ W1, const float* __restrict__ W2,
        u16* __restrict__ O0, u16* __restrict__ O1, u16* __restrict__ O2) {
    const float* W = blockIdx.z == 0 ? W0 : blockIdx.z == 1 ? W1 : W2;
    u16* O = blockIdx.z == 0 ? O0 : blockIdx.z == 1 ? O1 : O2;
    __shared__ float t[32][33];
    const int cx = threadIdx.x & 31, ry = threadIdx.x >> 5;
    const int d0 = blockIdx.x * 32, e0 = blockIdx.y * 32;
#pragma unroll
    for (int i = 0; i < 4; i++) t[ry + i * 8][cx] = W[(long)(d0 + ry + i * 8) * 1024 + e0 + cx];
    __syncthreads();
#pragma unroll
    for (int i = 0; i < 4; i++) O[(long)(e0 + ry + i * 8) * 1024 + d0 + cx] = f2bf(t[cx][ry + i * 8]);
}

// 3) V bf16 [4][2048][1024] -> Vt bf16 [4][1024][2048] ------------------------
__global__ __launch_bounds__(256) void vt_kernel(
        const u16* __restrict__ V, u16* __restrict__ Vt) {
    const int b = blockIdx.z;
    const u16* v = V + (long)b * 2048 * 1024;
    u16* o = Vt + (long)b * 1024 * 2048;
    __shared__ u16 t[32][33];
    const int cx = threadIdx.x & 31, ry = threadIdx.x >> 5;
    const int e0 = blockIdx.x * 32, t0 = blockIdx.y * 32;
#pragma unroll
    for (int i = 0; i < 4; i++) t[ry + i * 8][cx] = v[(long)(t0 + ry + i * 8) * 1024 + e0 + cx];
    __syncthreads();
#pragma unroll
    for (int i = 0; i < 4; i++) o[(long)(e0 + ry + i * 8) * 2048 + t0 + cx] = t[cx][ry + i * 8];
}

// 4) 256xBNT 8-phase GEMM: C = A[M][K] @ Bt[N][K]^T ---------------------------
// BM=256 always. BNT=256: round-3 verified schedule (wave-tile 128x64,
// 16 MFMA/phase, vmcnt(6) gates, LDS 128KB). BNT=128: wave-tile 128x32,
// 8 MFMA/phase, B = one 16KB unit/K-tile, vmcnt(4) gates, LDS 96KB
// (doubles grid for small-N GEMMs -> full GPU).
// MODE 0: QKV fused (bias, 3 split bf16 outputs, row stride 1024)
// MODE 1: scores (*scale, bf16 out, batched)
// MODE 2: PV (f32 out, batched)
template <int MODE, int BNT>
__global__ __launch_bounds__(512) void gemm8_kernel(
        const u16* __restrict__ A, const u16* __restrict__ Bt,
        void* __restrict__ out0, void* __restrict__ out1, void* __restrict__ out2,
        const float* __restrict__ b0, const float* __restrict__ b1, const float* __restrict__ b2,
        int K, int N, long sAb, long sBb, long sCb, float scale)
{
    extern __shared__ u16 lds[];
    constexpr int DB   = (BNT == 256) ? 32768 : 24576;  // u16 per dbuf (A 32KB + B 32/16KB)
    constexpr int FNH  = (BNT == 256) ? 2 : 1;          // B frags per NH
    constexpr int WCOL = (BNT == 256) ? 64 : 32;        // wave col width
    const int tid = threadIdx.x, lane = tid & 63, wid = tid >> 6;
    const int wm = wid >> 2, wn = wid & 3;
    const int l15 = lane & 15, hib = (lane >> 4) * 16;

    // XCD-aware bijective swizzle (all grids have nwg % 8 == 0)
    const int nbx = gridDim.x;
    const int nwg = nbx * gridDim.y;
    int lin = blockIdx.y * nbx + blockIdx.x;
    lin = (lin & 7) * (nwg >> 3) + (lin >> 3);
    const long m0 = (long)(lin / nbx) * 256;
    const long n0 = (long)(lin % nbx) * BNT;

    const u16* Ab = A + (long)blockIdx.z * sAb;
    const u16* Bb = Bt + (long)blockIdx.z * sBb;
    const long ldk = K;
    const int NT = K >> 6;          // K-tiles of 64

    // ---- staging ------------------------------------------------------------
    auto stA = [&](int dbuf, int S, int kt) {
#pragma unroll
        for (int i = 0; i < 2; ++i) {
            const int rl = tid >> 3;
            const int R  = S * 64 + rl;
            const int cb = (tid & 7) * 16;
            const int scb = cb ^ ((R & 7) << 4);        // inverse swizzle on SOURCE
            const u16* src = Ab + (m0 + i * 128 + R) * ldk + (long)kt * 64 + (scb >> 1);
            u16* dst = lds + dbuf * DB + i * 8192 + S * 4096 + wid * 512;
            gload_lds16(src, dst);
        }
    };
    auto stB = [&](int dbuf, int NHs, int kt) {   // BNT==256 only
#pragma unroll
        for (int i = 0; i < 2; ++i) {
            const int c = i * 2 + (wid >> 2);
            const int h = c >> 1, rb = (c & 1) * 64;
            const int w = (wid & 3) * 64 + lane;
            const int r32 = w >> 3;
            const int R = rb + NHs * 32 + r32;
            const int cb = (w & 7) * 16;
            const int scb = cb ^ ((R & 7) << 4);
            const u16* src = Bb + (n0 + h * 128 + R) * ldk + (long)kt * 64 + (scb >> 1);
            u16* dst = lds + dbuf * DB + 16384 + h * 8192 + (rb + NHs * 32) * 64 + (wid & 3) * 512;
            gload_lds16(src, dst);
        }
    };
    auto stB128 = [&](int dbuf, int kt) {          // BNT==128 only: one 128x64 unit
#pragma unroll
        for (int i = 0; i < 2; ++i) {
            const int R = i * 64 + (tid >> 3);
            const int cb = (tid & 7) * 16;
            const int scb = cb ^ ((R & 7) << 4);
            const u16* src = Bb + (n0 + R) * ldk + (long)kt * 64 + (scb >> 1);
            u16* dst = lds + dbuf * DB + 16384 + i * 4096 + tid * 8;
            gload_lds16(src, dst);
        }
    };

    floatx4 acc[8][2 * FNH] = {};
    short8 afr[4][2], bfr[FNH][2];

    auto LA = [&](int dbuf, auto MHc) {
        constexpr int MH = decltype(MHc)::value;
        const char* reg = (const char*)(lds + dbuf * DB + wm * 8192);
#pragma unroll
        for (int fm = 0; fm < 4; ++fm)
#pragma unroll
            for (int ks = 0; ks < 2; ++ks) {
                const int r = MH * 64 + fm * 16 + l15;
                const int cb = ks * 64 + hib;
                afr[fm][ks] = *(const short8*)(reg + r * 128 + (cb ^ ((r & 7) << 4)));
            }
    };
    auto LB = [&](int dbuf, auto NHc) {
        constexpr int NH = decltype(NHc)::value;
        if constexpr (BNT == 256) {
            const char* reg = (const char*)(lds + dbuf * DB + 16384 + (wn >> 1) * 8192);
#pragma unroll
            for (int fn = 0; fn < 2; ++fn)
#pragma unroll
                for (int ks = 0; ks < 2; ++ks) {
                    const int r = (wn & 1) * 64 + NH * 32 + fn * 16 + l15;
                    const int cb = ks * 64 + hib;
                    bfr[fn][ks] = *(const short8*)(reg + r * 128 + (cb ^ ((r & 7) << 4)));
                }
        } else {
            const char* reg = (const char*)(lds + dbuf * DB + 16384);
#pragma unroll
            for (int ks = 0; ks < 2; ++ks) {
                const int r = wn * 32 + NH * 16 + l15;
                const int cb = ks * 64 + hib;
                bfr[0][ks] = *(const short8*)(reg + r * 128 + (cb ^ ((r & 7) << 4)));
            }
        }
    };
    auto MM = [&](auto MHc, auto NHc) {
        constexpr int MH = decltype(MHc)::value;
        constexpr int NH = decltype(NHc)::value;
        __builtin_amdgcn_s_setprio(1);
#pragma unroll
        for (int fm = 0; fm < 4; ++fm)
#pragma unroll
            for (int fn = 0; fn < FNH; ++fn)
#pragma unroll
                for (int ks = 0; ks < 2; ++ks)
                    acc[MH * 4 + fm][NH * FNH + fn] = __builtin_amdgcn_mfma_f32_16x16x32_bf16(
                        afr[fm][ks], bfr[fn][ks], acc[MH * 4 + fm][NH * FNH + fn], 0, 0, 0);
        __builtin_amdgcn_s_setprio(0);
    };

#define BAR()   __builtin_amdgcn_s_barrier()
#define WAIT0() asm volatile("s_waitcnt lgkmcnt(0)" ::: "memory")

    // ---- prologue ------------------------------------------------------------
    if constexpr (BNT == 256) {
        stA(0, 0, 0); stA(0, 1, 0); stB(0, 0, 0); stB(0, 1, 0);
        stA(1, 0, 1); stB(1, 1, 1); stA(1, 1, 1);
        asm volatile("s_waitcnt vmcnt(6)");
    } else {
        stA(0, 0, 0); stA(0, 1, 0); stB128(0, 0);
        stA(1, 0, 1); stA(1, 1, 1);
        asm volatile("s_waitcnt vmcnt(4)");
    }
    BAR();

    // ---- main loop: one iteration = 2 K-tiles = 8 phases ----------------------
    auto pair = [&](auto LASTC, int kt0) {
        constexpr bool L = decltype(LASTC)::value;
        if constexpr (BNT == 256) {
            // === round-3 verified schedule ===
            LA(0, IC(0)); LB(0, IC(0));
            stB(1, 0, kt0 + 1);
            asm volatile("s_waitcnt lgkmcnt(8)");
            BAR(); WAIT0(); MM(IC(0), IC(0)); BAR();
            LB(0, IC(1));
            if (!L) stA(0, 0, kt0 + 2);
            BAR(); WAIT0(); MM(IC(0), IC(1)); BAR();
            LA(0, IC(1));
            if (!L) stB(0, 1, kt0 + 2);
            BAR(); WAIT0(); MM(IC(1), IC(1)); BAR();
            LB(0, IC(0));
            if (!L) stA(0, 1, kt0 + 2);
            BAR(); WAIT0(); MM(IC(1), IC(0));
            if (L) asm volatile("s_waitcnt vmcnt(0)");
            else   asm volatile("s_waitcnt vmcnt(6)");
            BAR();
            LA(1, IC(0)); LB(1, IC(0));
            if (!L) stB(0, 0, kt0 + 2);
            asm volatile("s_waitcnt lgkmcnt(8)");
            BAR(); WAIT0(); MM(IC(0), IC(0)); BAR();
            LB(1, IC(1));
            if (!L) stA(1, 0, kt0 + 3);
            BAR(); WAIT0(); MM(IC(0), IC(1)); BAR();
            LA(1, IC(1));
            if (!L) stB(1, 1, kt0 + 3);
            BAR(); WAIT0(); MM(IC(1), IC(1)); BAR();
            LB(1, IC(0));
            if (!L) stA(1, 1, kt0 + 3);
            BAR(); WAIT0(); MM(IC(1), IC(0));
            if (L) asm volatile("s_waitcnt vmcnt(0)");
            else   asm volatile("s_waitcnt vmcnt(6)");
            BAR();
        } else {
            // === BNT=128: same skeleton, 3 stage-units/kt, vmcnt(4) gates ===
            LA(0, IC(0)); LB(0, IC(0));
            stB128(1, kt0 + 1);
            asm volatile("s_waitcnt lgkmcnt(8)");
            BAR(); WAIT0(); MM(IC(0), IC(0)); BAR();
            LB(0, IC(1));
            if (!L) stA(0, 0, kt0 + 2);
            BAR(); WAIT0(); MM(IC(0), IC(1)); BAR();
            LA(0, IC(1));
            if (!L) stA(0, 1, kt0 + 2);
            BAR(); WAIT0(); MM(IC(1), IC(1)); BAR();
            LB(0, IC(0));
            BAR(); WAIT0(); MM(IC(1), IC(0));
            if (L) asm volatile("s_waitcnt vmcnt(0)");
            else   asm volatile("s_waitcnt vmcnt(4)");
            BAR();
            LA(1, IC(0)); LB(1, IC(0));
            if (!L) stB128(0, kt0 + 2);
            asm volatile("s_waitcnt lgkmcnt(8)");
            BAR(); WAIT0(); MM(IC(0), IC(0)); BAR();
            LB(1, IC(1));
            if (!L) stA(1, 0, kt0 + 3);
            BAR(); WAIT0(); MM(IC(0), IC(1)); BAR();
            LA(1, IC(1));
            if (!L) stA(1, 1, kt0 + 3);
            BAR(); WAIT0(); MM(IC(1), IC(1)); BAR();
            LB(1, IC(0));
            BAR(); WAIT0(); MM(IC(1), IC(0));
            if (L) asm volatile("s_waitcnt vmcnt(0)");
            else   asm volatile("s_waitcnt vmcnt(4)");
            BAR();
        }
    };

    const int NITER = NT >> 1;
    int it = 0;
    for (; it < NITER - 1; ++it) pair(std::false_type{}, 2 * it);
    pair(std::true_type{}, 2 * it);

#undef BAR
#undef WAIT0

    // ---- epilogue: C/D layout col=lane&15, row=(lane>>4)*4+j (HW-verified) ---
    const int cr = (lane >> 4) * 4, cc = l15;
    if (MODE == 0) {
        const int sel = (int)(n0 >> 10);
        u16* O = (u16*)(sel == 0 ? out0 : sel == 1 ? out1 : out2);
        const float* bias = sel == 0 ? b0 : sel == 1 ? b1 : b2;
        const long nc0 = n0 & 1023;
#pragma unroll
        for (int an = 0; an < 2 * FNH; ++an) {
            const long col = nc0 + wn * WCOL + an * 16 + cc;
            const float bvv = bias[col];
#pragma unroll
            for (int am = 0; am < 8; ++am) {
                const long row = m0 + wm * 128 + am * 16 + cr;
#pragma unroll
                for (int j = 0; j < 4; ++j)
                    O[(row + j) * 1024 + col] = f2bf(acc[am][an][j] + bvv);
            }
        }
    } else {
#pragma unroll
        for (int an = 0; an < 2 * FNH; ++an) {
            const long col = n0 + wn * WCOL + an * 16 + cc;
#pragma unroll
            for (int am = 0; am < 8; ++am) {
                const long row = m0 + wm * 128 + am * 16 + cr;
#pragma unroll
                for (int j = 0; j < 4; ++j) {
                    const long idx = (long)blockIdx.z * sCb + (row + j) * (long)N + col;
                    if (MODE == 1) ((u16*)out0)[idx] = f2bf(acc[am][an][j] * scale);
                    else           ((float*)out0)[idx] = acc[am][an][j];
                }
            }
        }
    }
}

// 5) in-place row softmax over 2048 bf16 --------------------------------------
__global__ __launch_bounds__(256) void softmax_kernel(u16* __restrict__ S) {
    u16* p = S + (long)blockIdx.x * 2048;
    const int tid = threadIdx.x;
    union { int4 q; u16 u[8]; } in;
    in.q = *(const int4*)(p + tid * 8);
    float v[8];
#pragma unroll
    for (int i = 0; i < 8; i++) v[i] = bf2f(in.u[i]);
    float mx = v[0];
#pragma unroll
    for (int i = 1; i < 8; i++) mx = fmaxf(mx, v[i]);
#pragma unroll
    for (int off = 32; off; off >>= 1) mx = fmaxf(mx, __shfl_xor(mx, off));
    __shared__ float red[8];
    if ((tid & 63) == 0) red[tid >> 6] = mx;
    __syncthreads();
    mx = fmaxf(fmaxf(red[0], red[1]), fmaxf(red[2], red[3]));
    float s = 0.f;
#pragma unroll
    for (int i = 0; i < 8; i++) { v[i] = __expf(v[i] - mx); s += v[i]; }
#pragma unroll
    for (int off = 32; off; off >>= 1) s += __shfl_xor(s, off);
    if ((tid & 63) == 0) red[4 + (tid >> 6)] = s;
    __syncthreads();
    s = red[4] + red[5] + red[6] + red[7];
    const float inv = 1.f / s;
    union { int4 q; u16 u[8]; } out;
#pragma unroll
    for (int i = 0; i < 8; i++) out.u[i] = f2bf(v[i] * inv);
    *(int4*)(p + tid * 8) = out.q;
}

// -----------------------------------------------------------------------------
extern "C" void kernel_launch(void* const* d_in, const int* in_sizes, int n_in,
                              void* d_out, int out_size, void* d_ws, size_t ws_size,
                              hipStream_t stream) {
    const float* x  = (const float*)d_in[0];
    const float* Wq = (const float*)d_in[1];
    const float* bq = (const float*)d_in[2];
    const float* Wk = (const float*)d_in[3];
    const float* bk = (const float*)d_in[4];
    const float* Wv = (const float*)d_in[5];
    const float* bv = (const float*)d_in[6];
    float* out = (float*)d_out;

    char* ws = (char*)d_ws;
    const long MB = 1L << 20;
    u16* xb = (u16*)(ws);            // 16 MB  x bf16 [8192][1024]
    u16* wt = (u16*)(ws + 16 * MB);  // 6 MB   W{q,k,v}^T bf16 [3072][1024] stacked
    u16* Q  = (u16*)(ws + 22 * MB);  // 16 MB  [4][2048][1024]
    u16* Kb = (u16*)(ws + 38 * MB);  // 16 MB
    u16* Vb = (u16*)(ws + 54 * MB);  // 16 MB
    u16* Vt = (u16*)(ws + 70 * MB);  // 16 MB  [4][1024][2048]
    u16* Sc = (u16*)(ws + 86 * MB);  // 32 MB  scores/attn [4][2048][2048]

    (void)hipFuncSetAttribute((const void*)gemm8_kernel<0, 256>, hipFuncAttributeMaxDynamicSharedMemorySize, 131072);
    (void)hipFuncSetAttribute((const void*)gemm8_kernel<1, 256>, hipFuncAttributeMaxDynamicSharedMemorySize, 131072);
    (void)hipFuncSetAttribute((const void*)gemm8_kernel<2, 128>, hipFuncAttributeMaxDynamicSharedMemorySize, 131072);

    // x -> bf16
    cvt_f32_bf16_kernel<<<8192, 256, 0, stream>>>(x, xb);
    // W -> Wt bf16 (transposed, stacked)
    wt_kernel<<<dim3(32, 32, 3), 256, 0, stream>>>(Wq, Wk, Wv, wt, wt + 1024 * 1024, wt + 2 * 1024 * 1024);
    // fused QKV: [8192][1024] @ [3072][1024]^T + bias (M=8192, N=3072, K=1024)
    gemm8_kernel<0, 256><<<dim3(12, 32, 1), 512, 131072, stream>>>(
        xb, wt, Q, Kb, Vb, bq, bk, bv, 1024, 3072, 0, 0, 0, 1.f);
    // V -> V^T per batch
    vt_kernel<<<dim3(32, 64, 4), 256, 0, stream>>>(Vb, Vt);
    // scores = (Q @ K^T) / 32, bf16, batched (M=N=2048, K=1024)
    gemm8_kernel<1, 256><<<dim3(8, 8, 4), 512, 131072, stream>>>(
        Q, Kb, Sc, nullptr, nullptr, nullptr, nullptr, nullptr,
        1024, 2048, 2048L * 1024, 2048L * 1024, 2048L * 2048, 0.03125f);
    // softmax rows, in place
    softmax_kernel<<<8192, 256, 0, stream>>>(Sc);
    // out = attn @ V, f32 out, batched (M=2048, N=1024, K=2048) — BN=128 -> 256 blocks
    gemm8_kernel<2, 128><<<dim3(8, 8, 4), 512, 98304, stream>>>(
        Sc, Vt, out, nullptr, nullptr, nullptr, nullptr, nullptr,
        2048, 1024, 2048L * 2048, 1024L * 2048, 2048L * 1024, 1.f);
}

// Round 6
// 181.936 us; speedup vs baseline: 1.6169x; 1.0117x over previous
//
#include <hip/hip_runtime.h>
#include <stdint.h>
#include <type_traits>

typedef unsigned short u16;
using short8  = __attribute__((ext_vector_type(8))) short;
using floatx4 = __attribute__((ext_vector_type(4))) float;

#define IC(n) (std::integral_constant<int, (n)>())

__device__ __forceinline__ u16 f2bf(float f) {
    unsigned u = __float_as_uint(f);
    u += 0x7fff + ((u >> 16) & 1);   // round-to-nearest-even
    return (u16)(u >> 16);
}
__device__ __forceinline__ float bf2f(u16 h) {
    return __uint_as_float(((unsigned)h) << 16);
}

// async global->LDS, 16B per lane (global_load_lds_dwordx4)
__device__ __forceinline__ void gload_lds16(const void* g, void* l) {
    auto gp = reinterpret_cast<const __attribute__((address_space(1))) unsigned int*>(
        reinterpret_cast<uintptr_t>(g));
    auto lp = reinterpret_cast<__attribute__((address_space(3))) unsigned int*>(
        reinterpret_cast<uintptr_t>(l));
    __builtin_amdgcn_global_load_lds(gp, lp, 16, 0, 0);
}

// 1) convert x f32 -> bf16 ----------------------------------------------------
__global__ __launch_bounds__(256) void cvt_f32_bf16_kernel(
        const float* __restrict__ in, u16* __restrict__ out) {
    long i = ((long)blockIdx.x * 256 + threadIdx.x) * 4;
    float4 v = *(const float4*)(in + i);
    ushort4 o;
    o.x = f2bf(v.x); o.y = f2bf(v.y); o.z = f2bf(v.z); o.w = f2bf(v.w);
    *(ushort4*)(out + i) = o;
}

// 2) W [1024][1024] f32 -> Wt bf16 [e][d] (transpose+convert), 3 weights ------
__global__ __launch_bounds__(256) void wt_kernel(
        const float* __restrict__ W0, const float* __restrict__ W1, const float* __restrict__ W2,
        u16* __restrict__ O0, u16* __restrict__ O1, u16* __restrict__ O2) {
    const float* W = blockIdx.z == 0 ? W0 : blockIdx.z == 1 ? W1 : W2;
    u16* O = blockIdx.z == 0 ? O0 : blockIdx.z == 1 ? O1 : O2;
    __shared__ float t[32][33];
    const int cx = threadIdx.x & 31, ry = threadIdx.x >> 5;
    const int d0 = blockIdx.x * 32, e0 = blockIdx.y * 32;
#pragma unroll
    for (int i = 0; i < 4; i++) t[ry + i * 8][cx] = W[(long)(d0 + ry + i * 8) * 1024 + e0 + cx];
    __syncthreads();
#pragma unroll
    for (int i = 0; i < 4; i++) O[(long)(e0 + ry + i * 8) * 1024 + d0 + cx] = f2bf(t[cx][ry + i * 8]);
}

// 3) V bf16 [4][2048][1024] -> Vt bf16 [4][1024][2048] ------------------------
__global__ __launch_bounds__(256) void vt_kernel(
        const u16* __restrict__ V, u16* __restrict__ Vt) {
    const int b = blockIdx.z;
    const u16* v = V + (long)b * 2048 * 1024;
    u16* o = Vt + (long)b * 1024 * 2048;
    __shared__ u16 t[32][33];
    const int cx = threadIdx.x & 31, ry = threadIdx.x >> 5;
    const int e0 = blockIdx.x * 32, t0 = blockIdx.y * 32;
#pragma unroll
    for (int i = 0; i < 4; i++) t[ry + i * 8][cx] = v[(long)(t0 + ry + i * 8) * 1024 + e0 + cx];
    __syncthreads();
#pragma unroll
    for (int i = 0; i < 4; i++) o[(long)(e0 + ry + i * 8) * 2048 + t0 + cx] = t[cx][ry + i * 8];
}

// 4) 256xBNT 8-phase GEMM: C = A[M][K] @ Bt[N][K]^T ---------------------------
// BM=256 always. Stage slots / vmcnt gates / barrier count identical to the
// round-3/5 verified schedule. ds_reads for quadrant k+1 are issued AFTER
// quadrant k's MFMA cluster (same phase, same barriers) so their drain hides
// in the matrix pipe's shadow; compiler emits counted lgkmcnt waits.
// MODE 0: QKV fused (bias, 3 split bf16 outputs, row stride 1024)
// MODE 1: scores (*scale, bf16 out, batched)
// MODE 2: PV (f32 out, batched)
template <int MODE, int BNT>
__global__ __launch_bounds__(512) void gemm8_kernel(
        const u16* __restrict__ A, const u16* __restrict__ Bt,
        void* __restrict__ out0, void* __restrict__ out1, void* __restrict__ out2,
        const float* __restrict__ b0, const float* __restrict__ b1, const float* __restrict__ b2,
        int K, int N, long sAb, long sBb, long sCb, float scale)
{
    extern __shared__ u16 lds[];
    constexpr int DB   = (BNT == 256) ? 32768 : 24576;  // u16 per dbuf
    constexpr int FNH  = (BNT == 256) ? 2 : 1;          // B frags per NH
    constexpr int WCOL = (BNT == 256) ? 64 : 32;        // wave col width
    const int tid = threadIdx.x, lane = tid & 63, wid = tid >> 6;
    const int wm = wid >> 2, wn = wid & 3;
    const int l15 = lane & 15, hib = (lane >> 4) * 16;

    // XCD-aware bijective swizzle (all grids have nwg % 8 == 0)
    const int nbx = gridDim.x;
    const int nwg = nbx * gridDim.y;
    int lin = blockIdx.y * nbx + blockIdx.x;
    lin = (lin & 7) * (nwg >> 3) + (lin >> 3);
    const long m0 = (long)(lin / nbx) * 256;
    const long n0 = (long)(lin % nbx) * BNT;

    const u16* Ab = A + (long)blockIdx.z * sAb;
    const u16* Bb = Bt + (long)blockIdx.z * sBb;
    const long ldk = K;
    const int NT = K >> 6;          // K-tiles of 64

    // ---- staging ------------------------------------------------------------
    auto stA = [&](int dbuf, int S, int kt) {
#pragma unroll
        for (int i = 0; i < 2; ++i) {
            const int rl = tid >> 3;
            const int R  = S * 64 + rl;
            const int cb = (tid & 7) * 16;
            const int scb = cb ^ ((R & 7) << 4);        // inverse swizzle on SOURCE
            const u16* src = Ab + (m0 + i * 128 + R) * ldk + (long)kt * 64 + (scb >> 1);
            u16* dst = lds + dbuf * DB + i * 8192 + S * 4096 + wid * 512;
            gload_lds16(src, dst);
        }
    };
    auto stB = [&](int dbuf, int NHs, int kt) {   // BNT==256 only
#pragma unroll
        for (int i = 0; i < 2; ++i) {
            const int c = i * 2 + (wid >> 2);
            const int h = c >> 1, rb = (c & 1) * 64;
            const int w = (wid & 3) * 64 + lane;
            const int r32 = w >> 3;
            const int R = rb + NHs * 32 + r32;
            const int cb = (w & 7) * 16;
            const int scb = cb ^ ((R & 7) << 4);
            const u16* src = Bb + (n0 + h * 128 + R) * ldk + (long)kt * 64 + (scb >> 1);
            u16* dst = lds + dbuf * DB + 16384 + h * 8192 + (rb + NHs * 32) * 64 + (wid & 3) * 512;
            gload_lds16(src, dst);
        }
    };
    auto stB128 = [&](int dbuf, int kt) {          // BNT==128 only: one 128x64 unit
#pragma unroll
        for (int i = 0; i < 2; ++i) {
            const int R = i * 64 + (tid >> 3);
            const int cb = (tid & 7) * 16;
            const int scb = cb ^ ((R & 7) << 4);
            const u16* src = Bb + (n0 + R) * ldk + (long)kt * 64 + (scb >> 1);
            u16* dst = lds + dbuf * DB + 16384 + i * 4096 + tid * 8;
            gload_lds16(src, dst);
        }
    };

    floatx4 acc[8][2 * FNH] = {};
    short8 afr[4][2], bfr[FNH][2];

    auto LA = [&](int dbuf, auto MHc) {
        constexpr int MH = decltype(MHc)::value;
        const char* reg = (const char*)(lds + dbuf * DB + wm * 8192);
#pragma unroll
        for (int fm = 0; fm < 4; ++fm)
#pragma unroll
            for (int ks = 0; ks < 2; ++ks) {
                const int r = MH * 64 + fm * 16 + l15;
                const int cb = ks * 64 + hib;
                afr[fm][ks] = *(const short8*)(reg + r * 128 + (cb ^ ((r & 7) << 4)));
            }
    };
    auto LB = [&](int dbuf, auto NHc) {
        constexpr int NH = decltype(NHc)::value;
        if constexpr (BNT == 256) {
            const char* reg = (const char*)(lds + dbuf * DB + 16384 + (wn >> 1) * 8192);
#pragma unroll
            for (int fn = 0; fn < 2; ++fn)
#pragma unroll
                for (int ks = 0; ks < 2; ++ks) {
                    const int r = (wn & 1) * 64 + NH * 32 + fn * 16 + l15;
                    const int cb = ks * 64 + hib;
                    bfr[fn][ks] = *(const short8*)(reg + r * 128 + (cb ^ ((r & 7) << 4)));
                }
        } else {
            const char* reg = (const char*)(lds + dbuf * DB + 16384);
#pragma unroll
            for (int ks = 0; ks < 2; ++ks) {
                const int r = wn * 32 + NH * 16 + l15;
                const int cb = ks * 64 + hib;
                bfr[0][ks] = *(const short8*)(reg + r * 128 + (cb ^ ((r & 7) << 4)));
            }
        }
    };
    auto MM = [&](auto MHc, auto NHc) {
        constexpr int MH = decltype(MHc)::value;
        constexpr int NH = decltype(NHc)::value;
        __builtin_amdgcn_s_setprio(1);
#pragma unroll
        for (int fm = 0; fm < 4; ++fm)
#pragma unroll
            for (int fn = 0; fn < FNH; ++fn)
#pragma unroll
                for (int ks = 0; ks < 2; ++ks)
                    acc[MH * 4 + fm][NH * FNH + fn] = __builtin_amdgcn_mfma_f32_16x16x32_bf16(
                        afr[fm][ks], bfr[fn][ks], acc[MH * 4 + fm][NH * FNH + fn], 0, 0, 0);
        __builtin_amdgcn_s_setprio(0);
    };

#define BAR() __builtin_amdgcn_s_barrier()

    // ---- prologue ------------------------------------------------------------
    if constexpr (BNT == 256) {
        stA(0, 0, 0); stA(0, 1, 0); stB(0, 0, 0); stB(0, 1, 0);
        stA(1, 0, 1); stB(1, 1, 1); stA(1, 1, 1);
        asm volatile("s_waitcnt vmcnt(6)");
    } else {
        stA(0, 0, 0); stA(0, 1, 0); stB128(0, 0);
        stA(1, 0, 1); stA(1, 1, 1);
        asm volatile("s_waitcnt vmcnt(4)");
    }
    BAR();

    // ---- main loop: one iteration = 2 K-tiles = 8 phases ----------------------
    // Stage slots & vmcnt gates == round-3/5 verified schedule. Reads for the
    // next quadrant issue after the current MFMA cluster (hidden drain).
    auto pair = [&](auto LASTC, int kt0) {
        constexpr bool L = decltype(LASTC)::value;
        if constexpr (BNT == 256) {
            // ph1 (kt0, dbuf0)
            stB(1, 0, kt0 + 1);
            LA(0, IC(0)); LB(0, IC(0));
            BAR(); MM(IC(0), IC(0)); LB(0, IC(1)); BAR();
            // ph2
            if (!L) stA(0, 0, kt0 + 2);
            BAR(); MM(IC(0), IC(1)); LA(0, IC(1)); BAR();
            // ph3
            if (!L) stB(0, 1, kt0 + 2);
            BAR(); MM(IC(1), IC(1)); LB(0, IC(0)); BAR();
            // ph4 + gate for dbuf1
            if (!L) stA(0, 1, kt0 + 2);
            BAR(); MM(IC(1), IC(0));
            if (L) asm volatile("s_waitcnt vmcnt(0)");
            else   asm volatile("s_waitcnt vmcnt(6)");
            BAR();
            // ph5 (kt0+1, dbuf1)
            if (!L) stB(0, 0, kt0 + 2);
            LA(1, IC(0)); LB(1, IC(0));
            BAR(); MM(IC(0), IC(0)); LB(1, IC(1)); BAR();
            // ph6
            if (!L) stA(1, 0, kt0 + 3);
            BAR(); MM(IC(0), IC(1)); LA(1, IC(1)); BAR();
            // ph7
            if (!L) stB(1, 1, kt0 + 3);
            BAR(); MM(IC(1), IC(1)); LB(1, IC(0)); BAR();
            // ph8 + gate for dbuf0
            if (!L) stA(1, 1, kt0 + 3);
            BAR(); MM(IC(1), IC(0));
            if (L) asm volatile("s_waitcnt vmcnt(0)");
            else   asm volatile("s_waitcnt vmcnt(6)");
            BAR();
        } else {
            // ph1 (kt0, dbuf0)
            stB128(1, kt0 + 1);
            LA(0, IC(0)); LB(0, IC(0));
            BAR(); MM(IC(0), IC(0)); LB(0, IC(1)); BAR();
            // ph2
            if (!L) stA(0, 0, kt0 + 2);
            BAR(); MM(IC(0), IC(1)); LA(0, IC(1)); BAR();
            // ph3
            if (!L) stA(0, 1, kt0 + 2);
            BAR(); MM(IC(1), IC(1)); LB(0, IC(0)); BAR();
            // ph4 + gate for dbuf1
            BAR(); MM(IC(1), IC(0));
            if (L) asm volatile("s_waitcnt vmcnt(0)");
            else   asm volatile("s_waitcnt vmcnt(4)");
            BAR();
            // ph5 (kt0+1, dbuf1)
            if (!L) stB128(0, kt0 + 2);
            LA(1, IC(0)); LB(1, IC(0));
            BAR(); MM(IC(0), IC(0)); LB(1, IC(1)); BAR();
            // ph6
            if (!L) stA(1, 0, kt0 + 3);
            BAR(); MM(IC(0), IC(1)); LA(1, IC(1)); BAR();
            // ph7
            if (!L) stA(1, 1, kt0 + 3);
            BAR(); MM(IC(1), IC(1)); LB(1, IC(0)); BAR();
            // ph8 + gate for dbuf0
            BAR(); MM(IC(1), IC(0));
            if (L) asm volatile("s_waitcnt vmcnt(0)");
            else   asm volatile("s_waitcnt vmcnt(4)");
            BAR();
        }
    };

    const int NITER = NT >> 1;
    int it = 0;
    for (; it < NITER - 1; ++it) pair(std::false_type{}, 2 * it);
    pair(std::true_type{}, 2 * it);

#undef BAR

    // ---- epilogue: C/D layout col=lane&15, row=(lane>>4)*4+j (HW-verified) ---
    const int cr = (lane >> 4) * 4, cc = l15;
    if (MODE == 0) {
        const int sel = (int)(n0 >> 10);
        u16* O = (u16*)(sel == 0 ? out0 : sel == 1 ? out1 : out2);
        const float* bias = sel == 0 ? b0 : sel == 1 ? b1 : b2;
        const long nc0 = n0 & 1023;
#pragma unroll
        for (int an = 0; an < 2 * FNH; ++an) {
            const long col = nc0 + wn * WCOL + an * 16 + cc;
            const float bvv = bias[col];
#pragma unroll
            for (int am = 0; am < 8; ++am) {
                const long row = m0 + wm * 128 + am * 16 + cr;
#pragma unroll
                for (int j = 0; j < 4; ++j)
                    O[(row + j) * 1024 + col] = f2bf(acc[am][an][j] + bvv);
            }
        }
    } else {
#pragma unroll
        for (int an = 0; an < 2 * FNH; ++an) {
            const long col = n0 + wn * WCOL + an * 16 + cc;
#pragma unroll
            for (int am = 0; am < 8; ++am) {
                const long row = m0 + wm * 128 + am * 16 + cr;
#pragma unroll
                for (int j = 0; j < 4; ++j) {
                    const long idx = (long)blockIdx.z * sCb + (row + j) * (long)N + col;
                    if (MODE == 1) ((u16*)out0)[idx] = f2bf(acc[am][an][j] * scale);
                    else           ((float*)out0)[idx] = acc[am][an][j];
                }
            }
        }
    }
}

// 5) in-place row softmax over 2048 bf16 --------------------------------------
__global__ __launch_bounds__(256) void softmax_kernel(u16* __restrict__ S) {
    u16* p = S + (long)blockIdx.x * 2048;
    const int tid = threadIdx.x;
    union { int4 q; u16 u[8]; } in;
    in.q = *(const int4*)(p + tid * 8);
    float v[8];
#pragma unroll
    for (int i = 0; i < 8; i++) v[i] = bf2f(in.u[i]);
    float mx = v[0];
#pragma unroll
    for (int i = 1; i < 8; i++) mx = fmaxf(mx, v[i]);
#pragma unroll
    for (int off = 32; off; off >>= 1) mx = fmaxf(mx, __shfl_xor(mx, off));
    __shared__ float red[8];
    if ((tid & 63) == 0) red[tid >> 6] = mx;
    __syncthreads();
    mx = fmaxf(fmaxf(red[0], red[1]), fmaxf(red[2], red[3]));
    float s = 0.f;
#pragma unroll
    for (int i = 0; i < 8; i++) { v[i] = __expf(v[i] - mx); s += v[i]; }
#pragma unroll
    for (int off = 32; off; off >>= 1) s += __shfl_xor(s, off);
    if ((tid & 63) == 0) red[4 + (tid >> 6)] = s;
    __syncthreads();
    s = red[4] + red[5] + red[6] + red[7];
    const float inv = 1.f / s;
    union { int4 q; u16 u[8]; } out;
#pragma unroll
    for (int i = 0; i < 8; i++) out.u[i] = f2bf(v[i] * inv);
    *(int4*)(p + tid * 8) = out.q;
}

// -----------------------------------------------------------------------------
extern "C" void kernel_launch(void* const* d_in, const int* in_sizes, int n_in,
                              void* d_out, int out_size, void* d_ws, size_t ws_size,
                              hipStream_t stream) {
    const float* x  = (const float*)d_in[0];
    const float* Wq = (const float*)d_in[1];
    const float* bq = (const float*)d_in[2];
    const float* Wk = (const float*)d_in[3];
    const float* bk = (const float*)d_in[4];
    const float* Wv = (const float*)d_in[5];
    const float* bv = (const float*)d_in[6];
    float* out = (float*)d_out;

    char* ws = (char*)d_ws;
    const long MB = 1L << 20;
    u16* xb = (u16*)(ws);            // 16 MB  x bf16 [8192][1024]
    u16* wt = (u16*)(ws + 16 * MB);  // 6 MB   W{q,k,v}^T bf16 [3072][1024] stacked
    u16* Q  = (u16*)(ws + 22 * MB);  // 16 MB  [4][2048][1024]
    u16* Kb = (u16*)(ws + 38 * MB);  // 16 MB
    u16* Vb = (u16*)(ws + 54 * MB);  // 16 MB
    u16* Vt = (u16*)(ws + 70 * MB);  // 16 MB  [4][1024][2048]
    u16* Sc = (u16*)(ws + 86 * MB);  // 32 MB  scores/attn [4][2048][2048]

    (void)hipFuncSetAttribute((const void*)gemm8_kernel<0, 256>, hipFuncAttributeMaxDynamicSharedMemorySize, 131072);
    (void)hipFuncSetAttribute((const void*)gemm8_kernel<1, 256>, hipFuncAttributeMaxDynamicSharedMemorySize, 131072);
    (void)hipFuncSetAttribute((const void*)gemm8_kernel<2, 128>, hipFuncAttributeMaxDynamicSharedMemorySize, 131072);

    // x -> bf16
    cvt_f32_bf16_kernel<<<8192, 256, 0, stream>>>(x, xb);
    // W -> Wt bf16 (transposed, stacked)
    wt_kernel<<<dim3(32, 32, 3), 256, 0, stream>>>(Wq, Wk, Wv, wt, wt + 1024 * 1024, wt + 2 * 1024 * 1024);
    // fused QKV: [8192][1024] @ [3072][1024]^T + bias (M=8192, N=3072, K=1024)
    gemm8_kernel<0, 256><<<dim3(12, 32, 1), 512, 131072, stream>>>(
        xb, wt, Q, Kb, Vb, bq, bk, bv, 1024, 3072, 0, 0, 0, 1.f);
    // V -> V^T per batch
    vt_kernel<<<dim3(32, 64, 4), 256, 0, stream>>>(Vb, Vt);
    // scores = (Q @ K^T) / 32, bf16, batched (M=N=2048, K=1024)
    gemm8_kernel<1, 256><<<dim3(8, 8, 4), 512, 131072, stream>>>(
        Q, Kb, Sc, nullptr, nullptr, nullptr, nullptr, nullptr,
        1024, 2048, 2048L * 1024, 2048L * 1024, 2048L * 2048, 0.03125f);
    // softmax rows, in place
    softmax_kernel<<<8192, 256, 0, stream>>>(Sc);
    // out = attn @ V, f32 out, batched (M=2048, N=1024, K=2048) — BN=128 -> 256 blocks
    gemm8_kernel<2, 128><<<dim3(8, 8, 4), 512, 98304, stream>>>(
        Sc, Vt, out, nullptr, nullptr, nullptr, nullptr, nullptr,
        2048, 1024, 2048L * 2048, 1024L * 2048, 2048L * 1024, 1.f);
}